// Round 9
// baseline (157.785 us; speedup 1.0000x reference)
//
#include <hip/hip_runtime.h>
#include <hip/hip_bf16.h>
#include <cstdint>
#include <cstddef>

#define BB 4
#define SEQ 2048
#define CD 768
#define NH 12
#define DH 64
#define MROWS (BB*SEQ)      // 8192
#define NQKV (3*CD)         // 2304

typedef float f32x4 __attribute__((ext_vector_type(4)));
typedef float f32x16 __attribute__((ext_vector_type(16)));
typedef short bf16x8 __attribute__((ext_vector_type(8)));

static __device__ __forceinline__ unsigned short f2bf(float f) {
  union { float f; unsigned int u; } cv; cv.f = f;
  unsigned int u = cv.u;
  unsigned int r = (u + 0x7FFFu + ((u >> 16) & 1u)) >> 16;
  return (unsigned short)r;
}

// raw v_exp_f32: our exponents are bounded (|x| <= ~23), no OCML fixups needed
static __device__ __forceinline__ float fexp2(float x) {
#if __has_builtin(__builtin_amdgcn_exp2f)
  return __builtin_amdgcn_exp2f(x);
#else
  float r; asm("v_exp_f32 %0, %1" : "=v"(r) : "v"(x)); return r;
#endif
}

#define GAS __attribute__((address_space(1)))
#define LAS __attribute__((address_space(3)))
static __device__ __forceinline__ void gl2lds16(const void* g, void* l) {
  __builtin_amdgcn_global_load_lds((const GAS void*)g, (LAS void*)l, 16, 0, 0);
}

#define MFMA(a, b, c) __builtin_amdgcn_mfma_f32_16x16x32_bf16((a), (b), (c), 0, 0, 0)
#define MFMA32(a, b, c) __builtin_amdgcn_mfma_f32_32x32x16_bf16((a), (b), (c), 0, 0, 0)
#define PACKBF(dst, x, y) asm("v_cvt_pk_bf16_f32 %0, %1, %2" : "=v"(dst) : "v"(x), "v"(y))
#define SWAP32(a, b) asm("v_permlane32_swap_b32 %0, %1" : "+v"(a), "+v"(b))

// 0.125 (1/sqrt(Dh)) * log2(e): folded into Q's gamma/beta so softmax uses exp2 directly.
// With LN'd q,k scores are bounded (|log2 score| <= 11.5) -> no max subtraction needed,
// which ALSO makes attention associative over keys: partial (O, l) sums just add.
#define QSC 0.18033688011112042f

// ---------------- fp32 -> bf16 convert ----------------
__global__ __launch_bounds__(256) void cvt_bf16(const float* __restrict__ in,
                                                unsigned short* __restrict__ out, int n4) {
  int i = blockIdx.x * 256 + threadIdx.x;
  if (i >= n4) return;
  float4 v = reinterpret_cast<const float4*>(in)[i];
  unsigned int lo = (unsigned int)f2bf(v.x) | ((unsigned int)f2bf(v.y) << 16);
  unsigned int hi = (unsigned int)f2bf(v.z) | ((unsigned int)f2bf(v.w) << 16);
  reinterpret_cast<uint2*>(out)[i] = make_uint2(lo, hi);
}

// ---------------- QKV GEMM: 128x128 tile, BK=64, 4 waves, swizzled LDS ----------------
__global__ __launch_bounds__(256) void qkv_gemm(
    const unsigned short* __restrict__ Xb, const unsigned short* __restrict__ Wb,
    const float* __restrict__ bias,
    const float* __restrict__ qg, const float* __restrict__ qbt,
    const float* __restrict__ kg, const float* __restrict__ kbt,
    unsigned short* __restrict__ Qo, unsigned short* __restrict__ Ko,
    unsigned short* __restrict__ Vt) {
  __shared__ unsigned short Als[2][128 * 64];   // 32KB
  __shared__ unsigned short Bls[2][128 * 64];   // 32KB
  const int tid = threadIdx.x;
  const int wid = tid >> 6, lane = tid & 63;
  const int g = lane >> 4, cl = lane & 15;
  const int wr = (wid >> 1) * 64, wc = (wid & 1) * 64;

  // XCD-bijective swizzle: grid 1152 = 8 * 144; contiguous wgid share bm (A-panel L2 reuse)
  const int wg = blockIdx.x;
  const int wgid = (wg & 7) * 144 + (wg >> 3);
  const int bm = wgid / 18, bn = wgid % 18;

  f32x4 acc[4][4] = {};

  const int srow = tid >> 3;                      // 0..31
  const int scol = ((tid & 7) ^ (srow & 7)) * 8;  // pre-swizzled source col
  const unsigned short* Abase = Xb + (size_t)(bm * 128 + srow) * CD + scol;
  const unsigned short* Bbase = Wb + (size_t)(bn * 128 + srow) * CD + scol;

#define QSTG(buf, kt)                                                         \
  do {                                                                        \
    gl2lds16(Abase + (size_t)0 * 32 * CD + (kt) * 64, &Als[buf][0 * 2048 + tid * 8]); \
    gl2lds16(Abase + (size_t)1 * 32 * CD + (kt) * 64, &Als[buf][1 * 2048 + tid * 8]); \
    gl2lds16(Abase + (size_t)2 * 32 * CD + (kt) * 64, &Als[buf][2 * 2048 + tid * 8]); \
    gl2lds16(Abase + (size_t)3 * 32 * CD + (kt) * 64, &Als[buf][3 * 2048 + tid * 8]); \
    gl2lds16(Bbase + (size_t)0 * 32 * CD + (kt) * 64, &Bls[buf][0 * 2048 + tid * 8]); \
    gl2lds16(Bbase + (size_t)1 * 32 * CD + (kt) * 64, &Bls[buf][1 * 2048 + tid * 8]); \
    gl2lds16(Bbase + (size_t)2 * 32 * CD + (kt) * 64, &Bls[buf][2 * 2048 + tid * 8]); \
    gl2lds16(Bbase + (size_t)3 * 32 * CD + (kt) * 64, &Bls[buf][3 * 2048 + tid * 8]); \
  } while (0)

  QSTG(0, 0);
  __syncthreads();
  const int NKT = CD / 64;  // 12
  for (int kt = 0; kt < NKT; ++kt) {
    const int cur = kt & 1;
    if (kt + 1 < NKT) QSTG(cur ^ 1, kt + 1);
    bf16x8 bfr[4][2];
#pragma unroll
    for (int j = 0; j < 4; ++j) {
      const int Bcol = wc + j * 16 + cl;
      const int sw = (Bcol & 7) << 3;
      bfr[j][0] = *(const bf16x8*)&Bls[cur][Bcol * 64 + ((g * 8) ^ sw)];
      bfr[j][1] = *(const bf16x8*)&Bls[cur][Bcol * 64 + ((32 + g * 8) ^ sw)];
    }
    __builtin_amdgcn_s_setprio(1);
#pragma unroll
    for (int i = 0; i < 4; ++i) {
      const int Arow = wr + i * 16 + cl;
      const int sw = (Arow & 7) << 3;
      bf16x8 a0 = *(const bf16x8*)&Als[cur][Arow * 64 + ((g * 8) ^ sw)];
      bf16x8 a1 = *(const bf16x8*)&Als[cur][Arow * 64 + ((32 + g * 8) ^ sw)];
#pragma unroll
      for (int j = 0; j < 4; ++j) {
        acc[i][j] = MFMA(a0, bfr[j][0], acc[i][j]);
        acc[i][j] = MFMA(a1, bfr[j][1], acc[i][j]);
      }
    }
    __builtin_amdgcn_s_setprio(0);
    __syncthreads();
  }
#undef QSTG

  const int j0 = bn * 128 + wc;
  const int t = j0 / CD;
  const int h = (j0 % CD) / DH;
  float bia[4], gam[4] = {0, 0, 0, 0}, bet[4] = {0, 0, 0, 0};
#pragma unroll
  for (int j = 0; j < 4; ++j) {
    int d = j * 16 + cl;
    bia[j] = bias[j0 + d];
    if (t == 0) { gam[j] = qg[d] * QSC; bet[j] = qbt[d] * QSC; }
    else if (t == 1) { gam[j] = kg[d]; bet[j] = kbt[d]; }
  }

  if (t == 2) {
#pragma unroll
    for (int i = 0; i < 4; ++i) {
      const int mrow = bm * 128 + wr + i * 16 + g * 4;
      const int b = mrow >> 11, nn = mrow & 2047;
#pragma unroll
      for (int j = 0; j < 4; ++j) {
        const int d = j * 16 + cl;
        unsigned int lo = (unsigned int)f2bf(acc[i][j][0] + bia[j]) |
                          ((unsigned int)f2bf(acc[i][j][1] + bia[j]) << 16);
        unsigned int hi2 = (unsigned int)f2bf(acc[i][j][2] + bia[j]) |
                           ((unsigned int)f2bf(acc[i][j][3] + bia[j]) << 16);
        *reinterpret_cast<uint2*>(&Vt[((size_t)(b * NH + h) * DH + d) * SEQ + nn]) =
            make_uint2(lo, hi2);
      }
    }
    return;
  }

  unsigned short* Out = (t == 0) ? Qo : Ko;
#pragma unroll
  for (int i = 0; i < 4; ++i) {
#pragma unroll
    for (int r = 0; r < 4; ++r) {
      float vj[4];
#pragma unroll
      for (int j = 0; j < 4; ++j) vj[j] = acc[i][j][r] + bia[j];
      const int m = bm * 128 + wr + i * 16 + g * 4 + r;
      const int b = m >> 11, n = m & 2047;
      size_t base = ((size_t)(b * NH + h) * SEQ + n) * DH;
      float s = vj[0] + vj[1] + vj[2] + vj[3];
      float ss = vj[0] * vj[0] + vj[1] * vj[1] + vj[2] * vj[2] + vj[3] * vj[3];
#pragma unroll
      for (int msk = 1; msk < 16; msk <<= 1) {
        s += __shfl_xor(s, msk, 64);
        ss += __shfl_xor(ss, msk, 64);
      }
      float mu = s * (1.0f / 64.0f);
      float var = ss * (1.0f / 64.0f) - mu * mu;
      float rstd = rsqrtf(var + 1e-5f);
#pragma unroll
      for (int j = 0; j < 4; ++j)
        Out[base + j * 16 + cl] = f2bf((vj[j] - mu) * rstd * gam[j] + bet[j]);
    }
  }
}

// ---------------- Flash attention: key-split waves ----------------
// Block = 64 q-rows, 4 waves: wave w -> qg = w&1 (which 32 q), kh = w>>1 (which key half).
// Each wave computes partial (O, l) over its 32 keys of each staged 64-key tile; partials
// are summed in f32 via LDS at the end (valid because no-max softmax is associative).
__global__ __launch_bounds__(256, 4) void attn_fwd(
    const unsigned short* __restrict__ Qb, const unsigned short* __restrict__ Kb,
    const unsigned short* __restrict__ Vtb, unsigned short* __restrict__ Ob) {
  __shared__ unsigned short kl[2][64 * 64];   // [key][d], 128B rows, XOR-swizzled
  __shared__ unsigned short vt[2][64 * 64];   // [d][key], 128B rows, XOR-swizzled
  const int tid = threadIdx.x, wave = tid >> 6, lane = tid & 63;
  const int q32 = lane & 31, hi = lane >> 5;
  const int qg = wave & 1, kh = wave >> 1;

  // XCD swizzle (T1): 1536 blocks = 8 * 192; each XCD owns 6 contiguous heads
  const int wg = blockIdx.x;
  const int lin = (wg & 7) * 192 + (wg >> 3);
  const int bh = lin >> 5;
  const int qbase = (lin & 31) * 64 + qg * 32;

  const unsigned short* qrow = Qb + ((size_t)bh * SEQ + qbase + q32) * DH + hi * 8;
  bf16x8 qf[4];
#pragma unroll
  for (int dc = 0; dc < 4; ++dc) qf[dc] = *(const bf16x8*)&qrow[dc * 16];

  const unsigned short* Kh = Kb + (size_t)bh * SEQ * DH;
  const unsigned short* Vth = Vtb + (size_t)bh * DH * SEQ;

  const int sr = tid >> 3;
  const int sc = 8 * ((tid & 7) ^ (sr & 7));
  const int ksw = (q32 & 7) << 3;
  const int krow = kh * 32 + q32;               // this wave's K rows (keys)

  const short oneb = (short)0x3F80;  // bf16 1.0
  const bf16x8 onesv = {oneb, oneb, oneb, oneb, oneb, oneb, oneb, oneb};

#define ASTAGE(buf, kb0)                                                      \
  do {                                                                        \
    gl2lds16(&Kh[(size_t)((kb0) + sr) * DH + sc], &kl[buf][tid * 8]);         \
    gl2lds16(&Kh[(size_t)((kb0) + sr + 32) * DH + sc], &kl[buf][tid * 8 + 2048]); \
    gl2lds16(&Vth[(size_t)sr * SEQ + (kb0) + sc], &vt[buf][tid * 8]);         \
    gl2lds16(&Vth[(size_t)(sr + 32) * SEQ + (kb0) + sc], &vt[buf][tid * 8 + 2048]); \
  } while (0)

  f32x16 o0 = {}, o1 = {}, ol = {};

  ASTAGE(0, 0);
  __syncthreads();
  const int NT = SEQ / 64;  // 32
#pragma unroll 2
  for (int it = 0; it < NT; ++it) {
    const int cur = it & 1;
    if (it + 1 < NT) ASTAGE(cur ^ 1, (it + 1) * 64);

    // S^T for this wave's 32 keys x 32 q
    f32x16 s = {};
    __builtin_amdgcn_s_setprio(1);
#pragma unroll
    for (int dc = 0; dc < 4; ++dc) {
      bf16x8 kf = *(const bf16x8*)&kl[cur][krow * 64 + ((dc * 16 + hi * 8) ^ ksw)];
      s = MFMA32(kf, qf[dc], s);
    }
    __builtin_amdgcn_s_setprio(0);

#pragma unroll
    for (int r = 0; r < 16; ++r) s[r] = fexp2(s[r]);

    // P -> bf16 A-frags: pav[c][i] = P[q][key_local = c*16 + 8*hi + i]
    bf16x8 pav[2];
#pragma unroll
    for (int c = 0; c < 2; ++c) {
      const int b = 8 * c;
      unsigned int wA0, wA1, wB0, wB1;
      PACKBF(wA0, s[b + 0], s[b + 1]); PACKBF(wA1, s[b + 2], s[b + 3]);
      PACKBF(wB0, s[b + 4], s[b + 5]); PACKBF(wB1, s[b + 6], s[b + 7]);
      SWAP32(wA0, wB0);
      SWAP32(wA1, wB1);
      union { unsigned int w[4]; bf16x8 v; } u;
      u.w[0] = wA0; u.w[1] = wA1; u.w[2] = wB0; u.w[3] = wB1;
      pav[c] = u.v;
    }

    // PV over this wave's 32 keys (cols kh*32 + c*16 + hi*8 of V^T)
    __builtin_amdgcn_s_setprio(1);
#pragma unroll
    for (int c = 0; c < 2; ++c) {
      const int colb = kh * 32 + c * 16 + hi * 8;
      bf16x8 vf0 = *(const bf16x8*)&vt[cur][q32 * 64 + (colb ^ ksw)];
      bf16x8 vf1 = *(const bf16x8*)&vt[cur][(32 + q32) * 64 + (colb ^ ksw)];
      o0 = MFMA32(pav[c], vf0, o0);
      o1 = MFMA32(pav[c], vf1, o1);
      ol = MFMA32(pav[c], onesv, ol);
    }
    __builtin_amdgcn_s_setprio(0);
    __syncthreads();
  }
#undef ASTAGE

  // combine key-half partials: kh=1 waves publish (O,l), kh=0 waves add + store.
  // LDS reuse is safe: all waves passed the final loop barrier (no more kl/vt reads).
  float* fb = qg ? (float*)&vt[0][0] : (float*)&kl[0][0];   // 12KB used of 16KB each
  if (kh == 1) {
#pragma unroll
    for (int r = 0; r < 16; ++r) {
      fb[r * 64 + lane] = o0[r];
      fb[1024 + r * 64 + lane] = o1[r];
      fb[2048 + r * 64 + lane] = ol[r];
    }
  }
  __syncthreads();
  if (kh == 0) {
    const int b = bh / NH, h = bh % NH;
#pragma unroll
    for (int r = 0; r < 16; ++r) {
      const float p0 = o0[r] + fb[r * 64 + lane];
      const float p1 = o1[r] + fb[1024 + r * 64 + lane];
      const float pl = ol[r] + fb[2048 + r * 64 + lane];
      const int qq = (r & 3) + 8 * (r >> 2) + 4 * hi;
      const float iv = __builtin_amdgcn_rcpf(pl);
      size_t base = ((size_t)(b * SEQ + qbase + qq)) * CD + h * DH;
      Ob[base + q32] = f2bf(p0 * iv);
      Ob[base + 32 + q32] = f2bf(p1 * iv);
    }
  }
}

// ---------------- Proj GEMM: 128x128 tile, BK=64, swizzled LDS, fp32 out ----------------
__global__ __launch_bounds__(256) void proj_gemm(
    const unsigned short* __restrict__ Ab, const unsigned short* __restrict__ Wb,
    const float* __restrict__ bias, float* __restrict__ out) {
  __shared__ unsigned short Als[2][128 * 64];   // 32KB
  __shared__ unsigned short Bls[2][128 * 64];   // 32KB
  const int tid = threadIdx.x;
  const int wid = tid >> 6, lane = tid & 63;
  const int g = lane >> 4, cl = lane & 15;
  const int bm = blockIdx.x, bn = blockIdx.y;
  const int wr = (wid >> 1) * 64, wc = (wid & 1) * 64;

  f32x4 acc[4][4] = {};

  const int srow = tid >> 3;                      // 0..31
  const int scol = ((tid & 7) ^ (srow & 7)) * 8;
  const unsigned short* Abase = Ab + (size_t)(bm * 128 + srow) * CD + scol;
  const unsigned short* Bbase = Wb + (size_t)(bn * 128 + srow) * CD + scol;

#define PSTG(buf, kt)                                                         \
  do {                                                                        \
    gl2lds16(Abase + (size_t)0 * 32 * CD + (kt) * 64, &Als[buf][0 * 2048 + tid * 8]); \
    gl2lds16(Abase + (size_t)1 * 32 * CD + (kt) * 64, &Als[buf][1 * 2048 + tid * 8]); \
    gl2lds16(Abase + (size_t)2 * 32 * CD + (kt) * 64, &Als[buf][2 * 2048 + tid * 8]); \
    gl2lds16(Abase + (size_t)3 * 32 * CD + (kt) * 64, &Als[buf][3 * 2048 + tid * 8]); \
    gl2lds16(Bbase + (size_t)0 * 32 * CD + (kt) * 64, &Bls[buf][0 * 2048 + tid * 8]); \
    gl2lds16(Bbase + (size_t)1 * 32 * CD + (kt) * 64, &Bls[buf][1 * 2048 + tid * 8]); \
    gl2lds16(Bbase + (size_t)2 * 32 * CD + (kt) * 64, &Bls[buf][2 * 2048 + tid * 8]); \
    gl2lds16(Bbase + (size_t)3 * 32 * CD + (kt) * 64, &Bls[buf][3 * 2048 + tid * 8]); \
  } while (0)

  PSTG(0, 0);
  __syncthreads();
  const int NKT = CD / 64;  // 12
  for (int kt = 0; kt < NKT; ++kt) {
    const int cur = kt & 1;
    if (kt + 1 < NKT) PSTG(cur ^ 1, kt + 1);
    bf16x8 bfr[4][2];
#pragma unroll
    for (int j = 0; j < 4; ++j) {
      const int Bcol = wc + j * 16 + cl;
      const int sw = (Bcol & 7) << 3;
      bfr[j][0] = *(const bf16x8*)&Bls[cur][Bcol * 64 + ((g * 8) ^ sw)];
      bfr[j][1] = *(const bf16x8*)&Bls[cur][Bcol * 64 + ((32 + g * 8) ^ sw)];
    }
    __builtin_amdgcn_s_setprio(1);
#pragma unroll
    for (int i = 0; i < 4; ++i) {
      const int Arow = wr + i * 16 + cl;
      const int sw = (Arow & 7) << 3;
      bf16x8 a0 = *(const bf16x8*)&Als[cur][Arow * 64 + ((g * 8) ^ sw)];
      bf16x8 a1 = *(const bf16x8*)&Als[cur][Arow * 64 + ((32 + g * 8) ^ sw)];
#pragma unroll
      for (int j = 0; j < 4; ++j) {
        acc[i][j] = MFMA(a0, bfr[j][0], acc[i][j]);
        acc[i][j] = MFMA(a1, bfr[j][1], acc[i][j]);
      }
    }
    __builtin_amdgcn_s_setprio(0);
    __syncthreads();
  }
#undef PSTG

  const int j0 = bn * 128 + wc;
  float pb4[4];
#pragma unroll
  for (int j = 0; j < 4; ++j) pb4[j] = bias[j0 + j * 16 + cl];
#pragma unroll
  for (int i = 0; i < 4; ++i) {
#pragma unroll
    for (int r = 0; r < 4; ++r) {
      const int m = bm * 128 + wr + i * 16 + g * 4 + r;
      float* orow = out + (size_t)m * CD + j0;
#pragma unroll
      for (int j = 0; j < 4; ++j) orow[j * 16 + cl] = acc[i][j][r] + pb4[j];
    }
  }
}

extern "C" void kernel_launch(void* const* d_in, const int* in_sizes, int n_in,
                              void* d_out, int out_size, void* d_ws, size_t ws_size,
                              hipStream_t stream) {
  const float* x = (const float*)d_in[0];
  const float* qkv_w = (const float*)d_in[1];
  const float* qkv_b = (const float*)d_in[2];
  const float* proj_w = (const float*)d_in[3];
  const float* proj_b = (const float*)d_in[4];
  const float* q_gamma = (const float*)d_in[5];
  const float* q_beta = (const float*)d_in[6];
  const float* k_gamma = (const float*)d_in[7];
  const float* k_beta = (const float*)d_in[8];
  float* out = (float*)d_out;

  char* w = (char*)d_ws;
  unsigned short* Xb = (unsigned short*)w; w += (size_t)MROWS * CD * 2;
  unsigned short* Wq = (unsigned short*)w; w += (size_t)NQKV * CD * 2;
  unsigned short* Wp = (unsigned short*)w; w += (size_t)CD * CD * 2;
  unsigned short* Qo = (unsigned short*)w; w += (size_t)BB * NH * SEQ * DH * 2;
  unsigned short* Ko = (unsigned short*)w; w += (size_t)BB * NH * SEQ * DH * 2;
  unsigned short* Vt = (unsigned short*)w; w += (size_t)BB * NH * SEQ * DH * 2;  // [b,h,d,n]
  unsigned short* Ob = (unsigned short*)w; w += (size_t)MROWS * CD * 2;

  cvt_bf16<<<MROWS * CD / 1024, 256, 0, stream>>>(x, Xb, MROWS * CD / 4);
  cvt_bf16<<<NQKV * CD / 1024, 256, 0, stream>>>(qkv_w, Wq, NQKV * CD / 4);
  cvt_bf16<<<CD * CD / 1024, 256, 0, stream>>>(proj_w, Wp, CD * CD / 4);

  qkv_gemm<<<(MROWS / 128) * (NQKV / 128), 256, 0, stream>>>(
      Xb, Wq, qkv_b, q_gamma, q_beta, k_gamma, k_beta, Qo, Ko, Vt);

  attn_fwd<<<(SEQ / 64) * BB * NH, 256, 0, stream>>>(Qo, Ko, Vt, Ob);

  proj_gemm<<<dim3(MROWS / 128, CD / 128), 256, 0, stream>>>(Ob, Wp, proj_b, out);
}